// Round 2
// baseline (550.359 us; speedup 1.0000x reference)
//
#include <hip/hip_runtime.h>
#include <hip/hip_cooperative_groups.h>

namespace cg = cooperative_groups;

// Screened Poisson Jacobi-PCG, B=4, H=W=1024, fp32, fixed 13 iterations.
//
// Primary path: SINGLE persistent cooperative kernel. CG state (r, p, wg, Md,
// halo p) lives in registers; x accumulates in global (one 16KB/block RMW per
// iteration, XCD-band L2-local); LDS use is ~300B so 4 blocks/CU co-residency
// is unambiguous. Kernel boundaries replaced by cg::grid.sync().
// Arithmetic (stencils, divisions, double partial accumulation order,
// shfl-tree reductions, per-batch alpha/beta) copied verbatim from the
// verified multi-kernel implementation, so the CG trajectory matches.
//
// Fallback path: the verified Round-0 multi-kernel implementation (540us),
// used if the cooperative launch cannot be placed (occupancy query < 4
// blocks/CU) or the cooperative launch call itself fails.

#define HH 1024
#define WW 1024
#define BB 4
#define NQUAD 1024         // 4096 rows / 4
#define NT 256
#define NWAVES (NT/64)
#define EPS_PC 1e-8f
#define EPS_DOT 1e-12
#define NIT 13

union F4 { float4 v; float a[4]; };
__device__ __forceinline__ float4 zf4(){ return make_float4(0.f,0.f,0.f,0.f); }

__device__ __forceinline__ double block_reduce(double v, double* lds){
  __syncthreads();
  #pragma unroll
  for (int o = 32; o > 0; o >>= 1) v += __shfl_down(v, o, 64);
  if ((threadIdx.x & 63) == 0) lds[threadIdx.x >> 6] = v;
  __syncthreads();
  if (threadIdx.x == 0){
    double s = lds[0];
    #pragma unroll
    for (int w = 1; w < NWAVES; w++) s += lds[w];
    lds[0] = s;
  }
  __syncthreads();
  return lds[0];
}

__device__ __forceinline__ void block_reduce2(double& v1, double& v2, double* lds){
  __syncthreads();
  #pragma unroll
  for (int o = 32; o > 0; o >>= 1){
    v1 += __shfl_down(v1, o, 64);
    v2 += __shfl_down(v2, o, 64);
  }
  if ((threadIdx.x & 63) == 0){
    lds[threadIdx.x >> 6] = v1;
    lds[NWAVES + (threadIdx.x >> 6)] = v2;
  }
  __syncthreads();
  if (threadIdx.x == 0){
    double s1 = lds[0], s2 = lds[NWAVES];
    #pragma unroll
    for (int w = 1; w < NWAVES; w++){ s1 += lds[w]; s2 += lds[NWAVES + w]; }
    lds[0] = s1; lds[NWAVES] = s2;
  }
  __syncthreads();
  v1 = lds[0]; v2 = lds[NWAVES];
}

__device__ __forceinline__ void block_reduce3(double& v1, double& v2, double& v3, double* lds){
  __syncthreads();
  #pragma unroll
  for (int o = 32; o > 0; o >>= 1){
    v1 += __shfl_down(v1, o, 64);
    v2 += __shfl_down(v2, o, 64);
    v3 += __shfl_down(v3, o, 64);
  }
  if ((threadIdx.x & 63) == 0){
    lds[threadIdx.x >> 6] = v1;
    lds[NWAVES + (threadIdx.x >> 6)] = v2;
    lds[2*NWAVES + (threadIdx.x >> 6)] = v3;
  }
  __syncthreads();
  if (threadIdx.x == 0){
    double s1 = lds[0], s2 = lds[NWAVES], s3 = lds[2*NWAVES];
    #pragma unroll
    for (int w = 1; w < NWAVES; w++){
      s1 += lds[w]; s2 += lds[NWAVES + w]; s3 += lds[2*NWAVES + w];
    }
    lds[0] = s1; lds[NWAVES] = s2; lds[2*NWAVES] = s3;
  }
  __syncthreads();
  v1 = lds[0]; v2 = lds[NWAVES]; v3 = lds[2*NWAVES];
}

// XCD-contiguous swizzle (1024 = 8*128, bijective): XCD k gets a contiguous
// 128-quad row band so N/S halo exchange stays within one XCD's L2.
__device__ __forceinline__ int swz1024(int bid){ return ((bid & 7) << 7) + (bid >> 3); }

// ===========================================================================
// Primary path: persistent cooperative PCG kernel
// ===========================================================================
__global__ void __launch_bounds__(NT, 4) k_pcg(
  const float* __restrict__ E, const float* __restrict__ DLp,
  const float* __restrict__ Mm, const float* __restrict__ lam,
  const float* __restrict__ mu, const float* __restrict__ wgp,
  float* __restrict__ xout,
  float* __restrict__ rtop, float* __restrict__ rbot,
  float* __restrict__ mdtop, float* __restrict__ mdbot,
  double* __restrict__ Rparts, double* __restrict__ Pparts)
{
  cg::grid_group grid = cg::this_grid();
  __shared__ float seamL[NWAVES][4], seamR[NWAVES][4];
  __shared__ double lds[NWAVES];

  const int tid = threadIdx.x;
  const int ln  = tid & 63;
  const int wvx = tid >> 6;
  const int q = swz1024(blockIdx.x);
  const int row0 = q * 4;
  const int b = row0 >> 10;          // batch index
  const int rr = row0 & (HH-1);
  const int c0 = tid * 4;
  const int base = row0 * WW + c0;
  const bool hasN = (rr > 0);
  const bool hasS = (rr < HH-4);

  F4 rreg[4], preg[4], wgr[4], wgN, md[4];
  float wwv[4];                      // west-neighbor wg per row (iteration-invariant)

  // ---------- setup: b -> r, p0=z, Md; write halo r/Md rows; rz0 partial ----------
  {
    F4 Em1, E0, wm1, w0;
    Em1.v = hasN ? *(const float4*)(E + base - WW)   : zf4();
    wm1.v = hasN ? *(const float4*)(wgp + base - WW) : zf4();
    E0.v  = *(const float4*)(E + base);
    w0.v  = *(const float4*)(wgp + base);
    wgN = wm1;

    double rz_acc = 0.0;
    #pragma unroll
    for (int k = 0; k < 4; k++){
      const int bk = base + k*WW;
      F4 Ep1, wp1, M4, L4, U4, D4;
      Ep1.v = (k < 3 || hasS) ? *(const float4*)(E + bk + WW) : zf4();
      wp1.v = (k < 3) ? *(const float4*)(wgp + bk + WW) : zf4();
      M4.v = *(const float4*)(Mm + bk);
      L4.v = *(const float4*)(lam + bk);
      U4.v = *(const float4*)(mu + bk);
      D4.v = *(const float4*)(DLp + bk);

      float Ew = __shfl_up(E0.a[3], 1, 64);
      float Ee = __shfl_down(E0.a[0], 1, 64);
      float ww_ = __shfl_up(w0.a[3], 1, 64);
      if (ln == 0 && c0 > 0){ Ew = E[bk-1]; ww_ = wgp[bk-1]; }
      if (ln == 63 && c0 + 4 < WW){ Ee = E[bk+4]; }

      const float ev[6]  = {Ew, E0.a[0], E0.a[1], E0.a[2], E0.a[3], Ee};
      const float wv5[5] = {ww_, w0.a[0], w0.a[1], w0.a[2], w0.a[3]};
      const bool rowHasN = (k > 0) || hasN;
      const bool rowHasS = (k < 3) || hasS;

      F4 r4, p4, m4;
      #pragma unroll
      for (int j = 0; j < 4; j++){
        const int c = c0 + j;
        const float cE = (c < WW-1) ? wv5[j+1] : 0.f;
        const float cW = (c > 0)    ? wv5[j]   : 0.f;
        const float cs = rowHasS ? wv5[j+1] : 0.f;
        const float cn = rowHasN ? wm1.a[j] : 0.f;
        const float u  = ev[j+1];
        const float me = U4.a[j] * M4.a[j];
        const float bv = cE*(ev[j+2]-u) - cW*(u-ev[j]) + cs*(Ep1.a[j]-u) - cn*(u-Em1.a[j])
                       + L4.a[j]*u + me*D4.a[j];
        const float mdv = L4.a[j] + me + cE + cW + cs + cn;
        const float z  = bv / (mdv + EPS_PC);
        r4.a[j] = bv; p4.a[j] = z; m4.a[j] = mdv;
        rz_acc += (double)bv * (double)z;
      }
      rreg[k] = r4; preg[k] = p4; wgr[k] = w0; wwv[k] = ww_; md[k] = m4;
      if (k == 0){
        *(float4*)(rtop + q*WW + c0)  = r4.v;
        *(float4*)(mdtop + q*WW + c0) = m4.v;
      }
      if (k == 3){
        *(float4*)(rbot + q*WW + c0)  = r4.v;
        *(float4*)(mdbot + q*WW + c0) = m4.v;
      }
      Em1 = E0; E0 = Ep1; wm1 = w0; w0 = wp1;   // shift window
    }
    const double s = block_reduce(rz_acc, lds);
    if (tid == 0) Rparts[q] = s;
  }

  grid.sync();

  F4 pNh, pSh;                       // halo p rows rr-1 / rr+4, kept recursively
  pNh.v = zf4(); pSh.v = zf4();
  double rz_red = 0.0;               // reduced rz_t (uniform across grid)
  float pw[4], pe[4];

  for (int t = 0; t < NIT; t++){
    // ---- phase A: beta_t + p-update (t>0) / halo-p init (t==0); Ap; pAp partial ----
    {
      double v = Rparts[(b << 8) + tid];
      v = block_reduce(v, lds);      // rz_t, full batch sum
      if (t == 0){
        rz_red = v;
        if (hasN){
          F4 rN, mN;
          rN.v = *(const float4*)(rbot  + (q-1)*WW + c0);
          mN.v = *(const float4*)(mdbot + (q-1)*WW + c0);
          #pragma unroll
          for (int j = 0; j < 4; j++) pNh.a[j] = rN.a[j] / (mN.a[j] + EPS_PC);
        }
        if (hasS){
          F4 rS, mS;
          rS.v = *(const float4*)(rtop  + (q+1)*WW + c0);
          mS.v = *(const float4*)(mdtop + (q+1)*WW + c0);
          #pragma unroll
          for (int j = 0; j < 4; j++) pSh.a[j] = rS.a[j] / (mS.a[j] + EPS_PC);
        }
      } else {
        const float beta = (float)(v / (rz_red + EPS_DOT));
        rz_red = v;
        if (hasN){
          F4 rN, mN;
          rN.v = *(const float4*)(rbot  + (q-1)*WW + c0);
          mN.v = *(const float4*)(mdbot + (q-1)*WW + c0);
          #pragma unroll
          for (int j = 0; j < 4; j++)
            pNh.a[j] = rN.a[j] / (mN.a[j] + EPS_PC) + beta * pNh.a[j];
        }
        if (hasS){
          F4 rS, mS;
          rS.v = *(const float4*)(rtop  + (q+1)*WW + c0);
          mS.v = *(const float4*)(mdtop + (q+1)*WW + c0);
          #pragma unroll
          for (int j = 0; j < 4; j++)
            pSh.a[j] = rS.a[j] / (mS.a[j] + EPS_PC) + beta * pSh.a[j];
        }
        #pragma unroll
        for (int k = 0; k < 4; k++){
          #pragma unroll
          for (int j = 0; j < 4; j++)
            preg[k].a[j] = rreg[k].a[j] / (md[k].a[j] + EPS_PC) + beta * preg[k].a[j];
        }
      }
    }

    // west/east seam exchange: shfl within wave, LDS across wave boundaries
    if (ln == 0){
      #pragma unroll
      for (int k = 0; k < 4; k++) seamL[wvx][k] = preg[k].a[0];
    }
    if (ln == 63){
      #pragma unroll
      for (int k = 0; k < 4; k++) seamR[wvx][k] = preg[k].a[3];
    }
    __syncthreads();
    #pragma unroll
    for (int k = 0; k < 4; k++){
      pw[k] = __shfl_up(preg[k].a[3], 1, 64);
      pe[k] = __shfl_down(preg[k].a[0], 1, 64);
    }
    if (ln == 0 && wvx > 0){
      #pragma unroll
      for (int k = 0; k < 4; k++) pw[k] = seamR[wvx-1][k];
    }
    if (ln == 63 && wvx < NWAVES-1){
      #pragma unroll
      for (int k = 0; k < 4; k++) pe[k] = seamL[wvx+1][k];
    }

    // Ap + pAp partial
    double acc = 0.0;
    #pragma unroll
    for (int k = 0; k < 4; k++){
      const float pa[6]  = {pw[k], preg[k].a[0], preg[k].a[1], preg[k].a[2], preg[k].a[3], pe[k]};
      const float wv5[5] = {wwv[k], wgr[k].a[0], wgr[k].a[1], wgr[k].a[2], wgr[k].a[3]};
      #pragma unroll
      for (int j = 0; j < 4; j++){
        const int c = c0 + j;
        const float cE = (c < WW-1) ? wv5[j+1] : 0.f;
        const float cW = (c > 0)    ? wv5[j]   : 0.f;
        const float cs = (k < 3) ? wgr[k].a[j] : (hasS ? wgr[3].a[j] : 0.f);
        const float cn = (k > 0) ? wgr[k-1].a[j] : (hasN ? wgN.a[j] : 0.f);
        const float psv = (k < 3) ? preg[k+1].a[j] : pSh.a[j];
        const float pnv = (k > 0) ? preg[k-1].a[j] : pNh.a[j];
        const float ap = md[k].a[j]*pa[j+1] - cE*pa[j+2] - cW*pa[j] - cs*psv - cn*pnv;
        acc += (double)ap * (double)pa[j+1];
      }
    }
    {
      const double s = block_reduce(acc, lds);
      if (tid == 0) Pparts[q] = s;
    }

    grid.sync();

    // ---- phase B: alpha_t; x += alpha p (global RMW); r -= alpha Ap; rz partial ----
    double v3 = Pparts[(b << 8) + tid];
    v3 = block_reduce(v3, lds);      // pAp_t, full batch sum
    const float alpha = (float)(rz_red / (v3 + EPS_DOT));

    #pragma unroll
    for (int k = 0; k < 4; k++){
      F4 xo;
      if (t > 0){
        F4 xc; xc.v = *(const float4*)(xout + base + k*WW);
        #pragma unroll
        for (int j = 0; j < 4; j++) xo.a[j] = xc.a[j] + alpha * preg[k].a[j];
      } else {
        #pragma unroll
        for (int j = 0; j < 4; j++) xo.a[j] = alpha * preg[k].a[j];
      }
      *(float4*)(xout + base + k*WW) = xo.v;
    }
    if (t == NIT-1) return;

    double rzacc = 0.0;
    #pragma unroll
    for (int k = 0; k < 4; k++){
      const float pa[6]  = {pw[k], preg[k].a[0], preg[k].a[1], preg[k].a[2], preg[k].a[3], pe[k]};
      const float wv5[5] = {wwv[k], wgr[k].a[0], wgr[k].a[1], wgr[k].a[2], wgr[k].a[3]};
      F4 rn4;
      #pragma unroll
      for (int j = 0; j < 4; j++){
        const int c = c0 + j;
        const float cE = (c < WW-1) ? wv5[j+1] : 0.f;
        const float cW = (c > 0)    ? wv5[j]   : 0.f;
        const float cs = (k < 3) ? wgr[k].a[j] : (hasS ? wgr[3].a[j] : 0.f);
        const float cn = (k > 0) ? wgr[k-1].a[j] : (hasN ? wgN.a[j] : 0.f);
        const float psv = (k < 3) ? preg[k+1].a[j] : pSh.a[j];
        const float pnv = (k > 0) ? preg[k-1].a[j] : pNh.a[j];
        const float ap = md[k].a[j]*pa[j+1] - cE*pa[j+2] - cW*pa[j] - cs*psv - cn*pnv;
        const float rn = rreg[k].a[j] - alpha * ap;
        rn4.a[j] = rn;
        rzacc += (double)rn * (double)(rn / (md[k].a[j] + EPS_PC));
      }
      rreg[k] = rn4;
      if (k == 0) *(float4*)(rtop + q*WW + c0) = rn4.v;
      if (k == 3) *(float4*)(rbot + q*WW + c0) = rn4.v;
    }
    {
      const double s2 = block_reduce(rzacc, lds);
      if (tid == 0) Rparts[q] = s2;
    }

    grid.sync();
  }
}

// ===========================================================================
// Fallback path: verified Round-0 multi-kernel implementation
// ===========================================================================
__global__ void __launch_bounds__(NT, 2) k_setup(
  const float* __restrict__ E, const float* __restrict__ DLp,
  const float* __restrict__ Mm, const float* __restrict__ lam,
  const float* __restrict__ mu, const float* __restrict__ wg,
  float* __restrict__ r, float* __restrict__ p0, float* __restrict__ Md,
  double* __restrict__ rz_parts)
{
  __shared__ double lds[3*NWAVES];
  const int tid = threadIdx.x;
  const int q = swz1024(blockIdx.x);
  const int row0 = q * 4;
  const int rr = row0 & (HH-1);
  const int c0 = tid * 4;
  const int base = row0 * WW + c0;
  const bool hasN = (rr > 0);
  const bool hasS = (rr < HH-4);

  F4 Em1, E0, wm1, w0;
  Em1.v = hasN ? *(const float4*)(E + base - WW)  : zf4();
  wm1.v = hasN ? *(const float4*)(wg + base - WW) : zf4();
  E0.v  = *(const float4*)(E + base);
  w0.v  = *(const float4*)(wg + base);

  double rz_acc = 0.0;
  #pragma unroll
  for (int k = 0; k < 4; k++){
    const int bk = base + k*WW;
    F4 Ep1, wp1, M4, L4, U4, D4;
    Ep1.v = (k < 3 || hasS) ? *(const float4*)(E + bk + WW) : zf4();
    wp1.v = (k < 3) ? *(const float4*)(wg + bk + WW) : zf4();
    M4.v = *(const float4*)(Mm + bk);
    L4.v = *(const float4*)(lam + bk);
    U4.v = *(const float4*)(mu + bk);
    D4.v = *(const float4*)(DLp + bk);

    float Ew = __shfl_up(E0.a[3], 1, 64);
    float Ee = __shfl_down(E0.a[0], 1, 64);
    float ww_ = __shfl_up(w0.a[3], 1, 64);
    if ((tid & 63) == 0 && c0 > 0){ Ew = E[bk-1]; ww_ = wg[bk-1]; }
    if ((tid & 63) == 63 && c0 + 4 < WW){ Ee = E[bk+4]; }

    const float ev[6] = {Ew, E0.a[0], E0.a[1], E0.a[2], E0.a[3], Ee};
    const float wv[5] = {ww_, w0.a[0], w0.a[1], w0.a[2], w0.a[3]};
    const bool rowHasN = (k > 0) || hasN;
    const bool rowHasS = (k < 3) || hasS;

    F4 r4, p4, m4;
    #pragma unroll
    for (int j = 0; j < 4; j++){
      const int c = c0 + j;
      const float cE = (c < WW-1) ? wv[j+1] : 0.f;
      const float cW = (c > 0)    ? wv[j]   : 0.f;
      const float cS = rowHasS ? wv[j+1] : 0.f;
      const float cN = rowHasN ? wm1.a[j] : 0.f;
      const float u  = ev[j+1];
      const float me = U4.a[j] * M4.a[j];
      const float bv = cE*(ev[j+2]-u) - cW*(u-ev[j]) + cS*(Ep1.a[j]-u) - cN*(u-Em1.a[j])
                     + L4.a[j]*u + me*D4.a[j];
      const float mdv = L4.a[j] + me + cE + cW + cS + cN;
      const float z  = bv / (mdv + EPS_PC);
      r4.a[j] = bv; p4.a[j] = z; m4.a[j] = mdv;
      rz_acc += (double)bv * (double)z;
    }
    *(float4*)(r + bk) = r4.v;
    *(float4*)(p0 + bk) = p4.v;
    *(float4*)(Md + bk) = m4.v;

    Em1 = E0; E0 = Ep1; wm1 = w0; w0 = wp1;   // shift window
  }
  const double s = block_reduce(rz_acc, lds);
  if (tid == 0) rz_parts[q] = s;
}

__global__ void __launch_bounds__(NT, 2) k_A(
  const float* __restrict__ r, const float* __restrict__ Md,
  const float* __restrict__ p_in, float* __restrict__ p_out,
  const float* __restrict__ wg, float* __restrict__ x,
  const double* __restrict__ Rprev, const double* __restrict__ Rcur,
  const double* __restrict__ Pprev, double* __restrict__ Pout, int t)
{
  __shared__ double lds[3*NWAVES];
  const int tid = threadIdx.x;
  const int q = swz1024(blockIdx.x);
  const int row0 = q * 4;
  const int b = row0 >> 10;
  const int rr = row0 & (HH-1);
  const int c0 = tid * 4;
  const int base = row0 * WW + c0;
  const bool hasN = (rr > 0);
  const bool hasS = (rr < HH-4);

  F4 wgr[4], md[4], wgN;
  #pragma unroll
  for (int k = 0; k < 4; k++){
    wgr[k].v = *(const float4*)(wg + base + k*WW);
    md[k].v  = *(const float4*)(Md + base + k*WW);
  }
  wgN.v = hasN ? *(const float4*)(wg + base - WW) : zf4();

  float pn[6][4];                        // p_new rows rr-1 .. rr+4
  float beta = 0.f;
  if (t == 0){
    F4 tN, tS, tc[4];
    tN.v = hasN ? *(const float4*)(p_in + base - WW) : zf4();
    #pragma unroll
    for (int k = 0; k < 4; k++) tc[k].v = *(const float4*)(p_in + base + k*WW);
    tS.v = hasS ? *(const float4*)(p_in + base + 4*WW) : zf4();
    #pragma unroll
    for (int j = 0; j < 4; j++){
      pn[0][j] = tN.a[j]; pn[5][j] = tS.a[j];
      #pragma unroll
      for (int k = 0; k < 4; k++) pn[k+1][j] = tc[k].a[j];
    }
  } else {
    F4 rcN, pcN, mN, rcS, pcS, mS, rc[4], pc[4];
    if (hasN){
      rcN.v = *(const float4*)(r + base - WW);
      pcN.v = *(const float4*)(p_in + base - WW);
      mN.v  = *(const float4*)(Md + base - WW);
    } else { rcN.v = zf4(); pcN.v = zf4(); mN.v = zf4(); }
    #pragma unroll
    for (int k = 0; k < 4; k++){
      rc[k].v = *(const float4*)(r + base + k*WW);
      pc[k].v = *(const float4*)(p_in + base + k*WW);
    }
    if (hasS){
      rcS.v = *(const float4*)(r + base + 4*WW);
      pcS.v = *(const float4*)(p_in + base + 4*WW);
      mS.v  = *(const float4*)(Md + base + 4*WW);
    } else { rcS.v = zf4(); pcS.v = zf4(); mS.v = zf4(); }

    double v1 = Rprev[(b << 8) + tid];
    double v2 = Rcur [(b << 8) + tid];
    double v3 = Pprev[(b << 8) + tid];
    block_reduce3(v1, v2, v3, lds);
    const float alpha_prev = (float)(v1 / (v3 + EPS_DOT));
    beta = (float)(v2 / (v1 + EPS_DOT));

    #pragma unroll
    for (int j = 0; j < 4; j++){
      pn[0][j] = hasN ? (rcN.a[j] / (mN.a[j] + EPS_PC) + beta * pcN.a[j]) : 0.f;
      pn[5][j] = hasS ? (rcS.a[j] / (mS.a[j] + EPS_PC) + beta * pcS.a[j]) : 0.f;
      #pragma unroll
      for (int k = 0; k < 4; k++)
        pn[k+1][j] = rc[k].a[j] / (md[k].a[j] + EPS_PC) + beta * pc[k].a[j];
    }
    #pragma unroll
    for (int k = 0; k < 4; k++){
      F4 o;
      #pragma unroll
      for (int j = 0; j < 4; j++) o.a[j] = pn[k+1][j];
      *(float4*)(p_out + base + k*WW) = o.v;
    }
    #pragma unroll
    for (int k = 0; k < 4; k++){
      F4 xo;
      if (t > 1){
        F4 xc; xc.v = *(const float4*)(x + base + k*WW);
        #pragma unroll
        for (int j = 0; j < 4; j++) xo.a[j] = xc.a[j] + alpha_prev * pc[k].a[j];
      } else {
        #pragma unroll
        for (int j = 0; j < 4; j++) xo.a[j] = alpha_prev * pc[k].a[j];
      }
      *(float4*)(x + base + k*WW) = xo.v;
    }
  }

  float pw[4], pe[4], ww[4];
  #pragma unroll
  for (int k = 0; k < 4; k++){
    pw[k] = __shfl_up(pn[k+1][3], 1, 64);
    pe[k] = __shfl_down(pn[k+1][0], 1, 64);
    ww[k] = __shfl_up(wgr[k].a[3], 1, 64);
  }
  if ((tid & 63) == 0 && c0 > 0){
    #pragma unroll
    for (int k = 0; k < 4; k++){
      const int bk = base + k*WW;
      pw[k] = (t == 0) ? p_in[bk-1]
                       : r[bk-1] / (Md[bk-1] + EPS_PC) + beta * p_in[bk-1];
      ww[k] = wg[bk-1];
    }
  }
  if ((tid & 63) == 63 && c0 + 4 < WW){
    #pragma unroll
    for (int k = 0; k < 4; k++){
      const int bk = base + k*WW;
      pe[k] = (t == 0) ? p_in[bk+4]
                       : r[bk+4] / (Md[bk+4] + EPS_PC) + beta * p_in[bk+4];
    }
  }

  double acc = 0.0;
  #pragma unroll
  for (int k = 0; k < 4; k++){
    const float pa[6] = {pw[k], pn[k+1][0], pn[k+1][1], pn[k+1][2], pn[k+1][3], pe[k]};
    const float wv[5] = {ww[k], wgr[k].a[0], wgr[k].a[1], wgr[k].a[2], wgr[k].a[3]};
    #pragma unroll
    for (int j = 0; j < 4; j++){
      const int c = c0 + j;
      const float cE = (c < WW-1) ? wv[j+1] : 0.f;
      const float cW = (c > 0)    ? wv[j]   : 0.f;
      const float cS = (k < 3) ? wgr[k].a[j] : (hasS ? wgr[3].a[j] : 0.f);
      const float cN = (k > 0) ? wgr[k-1].a[j] : (hasN ? wgN.a[j] : 0.f);
      const float ap = md[k].a[j]*pa[j+1] - cE*pa[j+2] - cW*pa[j]
                     - cS*pn[k+2][j] - cN*pn[k][j];
      acc += (double)ap * (double)pa[j+1];
    }
  }
  const double s = block_reduce(acc, lds);
  if (tid == 0) Pout[q] = s;
}

__global__ void __launch_bounds__(NT, 2) k_B(
  float* __restrict__ r, const float* __restrict__ p,
  const float* __restrict__ wg, const float* __restrict__ Md,
  const double* __restrict__ Rcur, const double* __restrict__ Pcur,
  double* __restrict__ Rnext)
{
  __shared__ double lds[3*NWAVES];
  const int tid = threadIdx.x;
  const int q = swz1024(blockIdx.x);
  const int row0 = q * 4;
  const int b = row0 >> 10;
  const int rr = row0 & (HH-1);
  const int c0 = tid * 4;
  const int base = row0 * WW + c0;
  const bool hasN = (rr > 0);
  const bool hasS = (rr < HH-4);

  F4 pc[4], wgr[4], md[4], rc[4], pHN, pHS, wgN;
  #pragma unroll
  for (int k = 0; k < 4; k++){
    pc[k].v  = *(const float4*)(p + base + k*WW);
    wgr[k].v = *(const float4*)(wg + base + k*WW);
    md[k].v  = *(const float4*)(Md + base + k*WW);
    rc[k].v  = *(const float4*)(r + base + k*WW);
  }
  pHN.v = hasN ? *(const float4*)(p + base - WW)  : zf4();
  wgN.v = hasN ? *(const float4*)(wg + base - WW) : zf4();
  pHS.v = hasS ? *(const float4*)(p + base + 4*WW) : zf4();

  double v1 = Rcur[(b << 8) + tid];
  double v2 = Pcur[(b << 8) + tid];
  block_reduce2(v1, v2, lds);
  const float alpha = (float)(v1 / (v2 + EPS_DOT));

  float pw[4], pe[4], ww[4];
  #pragma unroll
  for (int k = 0; k < 4; k++){
    pw[k] = __shfl_up(pc[k].a[3], 1, 64);
    pe[k] = __shfl_down(pc[k].a[0], 1, 64);
    ww[k] = __shfl_up(wgr[k].a[3], 1, 64);
  }
  if ((tid & 63) == 0 && c0 > 0){
    #pragma unroll
    for (int k = 0; k < 4; k++){
      pw[k] = p[base + k*WW - 1];
      ww[k] = wg[base + k*WW - 1];
    }
  }
  if ((tid & 63) == 63 && c0 + 4 < WW){
    #pragma unroll
    for (int k = 0; k < 4; k++) pe[k] = p[base + k*WW + 4];
  }

  double rz_acc = 0.0;
  #pragma unroll
  for (int k = 0; k < 4; k++){
    const float pa[6] = {pw[k], pc[k].a[0], pc[k].a[1], pc[k].a[2], pc[k].a[3], pe[k]};
    const float wv[5] = {ww[k], wgr[k].a[0], wgr[k].a[1], wgr[k].a[2], wgr[k].a[3]};
    F4 ro;
    #pragma unroll
    for (int j = 0; j < 4; j++){
      const int c = c0 + j;
      const float cE = (c < WW-1) ? wv[j+1] : 0.f;
      const float cW = (c > 0)    ? wv[j]   : 0.f;
      const float cS = (k < 3) ? wgr[k].a[j] : (hasS ? wgr[3].a[j] : 0.f);
      const float cN = (k > 0) ? wgr[k-1].a[j] : (hasN ? wgN.a[j] : 0.f);
      const float pS = (k < 3) ? pc[k+1].a[j] : pHS.a[j];
      const float pN = (k > 0) ? pc[k-1].a[j] : pHN.a[j];
      const float ap = md[k].a[j]*pa[j+1] - cE*pa[j+2] - cW*pa[j] - cS*pS - cN*pN;
      const float rn = rc[k].a[j] - alpha * ap;
      ro.a[j] = rn;
      const double rd = (double)rn;
      rz_acc += rd * (double)(rn / (md[k].a[j] + EPS_PC));
    }
    *(float4*)(r + base + k*WW) = ro.v;
  }
  const double s = block_reduce(rz_acc, lds);
  if (tid == 0) Rnext[q] = s;
}

__global__ void __launch_bounds__(NT, 2) k_X(
  float* __restrict__ x, const float* __restrict__ p,
  const double* __restrict__ Rcur, const double* __restrict__ Pcur)
{
  __shared__ double lds[3*NWAVES];
  const int tid = threadIdx.x;
  const int q = swz1024(blockIdx.x);
  const int row0 = q * 4;
  const int b = row0 >> 10;
  const int c0 = tid * 4;
  const int base = row0 * WW + c0;

  F4 pc[4], xc[4];
  #pragma unroll
  for (int k = 0; k < 4; k++){
    pc[k].v = *(const float4*)(p + base + k*WW);
    xc[k].v = *(const float4*)(x + base + k*WW);
  }
  double v1 = Rcur[(b << 8) + tid];
  double v2 = Pcur[(b << 8) + tid];
  block_reduce2(v1, v2, lds);
  const float alpha = (float)(v1 / (v2 + EPS_DOT));

  #pragma unroll
  for (int k = 0; k < 4; k++){
    F4 xo;
    #pragma unroll
    for (int j = 0; j < 4; j++) xo.a[j] = xc[k].a[j] + alpha * pc[k].a[j];
    *(float4*)(x + base + k*WW) = xo.v;
  }
}

// ===========================================================================
// Host launcher
// ===========================================================================
static void launch_fallback(const float* E, const float* DL, const float* Mm,
                            const float* lam, const float* mu, const float* wg,
                            float* x, void* d_ws, hipStream_t stream)
{
  const int N = BB*HH*WW;
  float* r  = (float*)d_ws;
  float* p0 = r  + N;
  float* p1 = p0 + N;
  float* Md = p1 + N;
  double* R0 = (double*)(Md + N);      // rz rotation [3][NQUAD]
  double* R1 = R0 + NQUAD;
  double* R2 = R1 + NQUAD;
  double* P0 = R2 + NQUAD;             // pAp ping-pong [2][NQUAD]
  double* P1 = P0 + NQUAD;

  double* R[3] = { R0, R1, R2 };
  double* P[2] = { P0, P1 };

  k_setup<<<NQUAD, NT, 0, stream>>>(E, DL, Mm, lam, mu, wg, r, p0, Md, R0);

  for (int t = 0; t < NIT; t++){
    float* p_cur = (t & 1) ? p1 : p0;                          // p_t
    const float* p_in = (t == 0) ? p0 : ((t & 1) ? p0 : p1);   // p_{t-1}
    k_A<<<NQUAD, NT, 0, stream>>>(r, Md, p_in, p_cur, wg, x,
                                  R[(t+2)%3], R[t%3], P[(t+1)&1], P[t&1], t);
    if (t < NIT-1)
      k_B<<<NQUAD, NT, 0, stream>>>(r, p_cur, wg, Md, R[t%3], P[t&1], R[(t+1)%3]);
  }
  k_X<<<NQUAD, NT, 0, stream>>>(x, (NIT-1) & 1 ? p1 : p0, R[(NIT-1)%3], P[(NIT-1)&1]);
}

extern "C" void kernel_launch(void* const* d_in, const int* in_sizes, int n_in,
                              void* d_out, int out_size, void* d_ws, size_t ws_size,
                              hipStream_t stream)
{
  (void)in_sizes; (void)n_in; (void)out_size; (void)ws_size;
  const float* E   = (const float*)d_in[0];
  const float* DLp = (const float*)d_in[1];
  const float* Mm  = (const float*)d_in[2];
  const float* lam = (const float*)d_in[3];
  const float* mu  = (const float*)d_in[4];
  const float* wgp = (const float*)d_in[5];
  float* xout = (float*)d_out;

  // Decide once whether the cooperative persistent kernel can be placed:
  // need >= 4 blocks/CU so that 1024 blocks co-reside on 256 CUs.
  static int coop_ok = -1;
  if (coop_ok < 0){
    int nb = 0;
    hipError_t e = hipOccupancyMaxActiveBlocksPerMultiprocessor(&nb, k_pcg, NT, 0);
    coop_ok = (e == hipSuccess && nb >= 4) ? 1 : 0;
  }

  if (coop_ok){
    // persistent-path workspace (16 MB + 16 KB; disjoint use from fallback
    // layout, but may alias it since exactly one path runs per launch)
    float* rtop  = (float*)d_ws;                 // [NQUAD][WW] r row rr
    float* rbot  = rtop  + NQUAD*WW;             // [NQUAD][WW] r row rr+3
    float* mdtop = rbot  + NQUAD*WW;             // [NQUAD][WW] Md row rr
    float* mdbot = mdtop + NQUAD*WW;             // [NQUAD][WW] Md row rr+3
    double* Rparts = (double*)(mdbot + NQUAD*WW);// [NQUAD] rz partials
    double* Pparts = Rparts + NQUAD;             // [NQUAD] pAp partials

    void* args[13] = { (void*)&E, (void*)&DLp, (void*)&Mm, (void*)&lam,
                       (void*)&mu, (void*)&wgp, (void*)&xout,
                       (void*)&rtop, (void*)&rbot, (void*)&mdtop, (void*)&mdbot,
                       (void*)&Rparts, (void*)&Pparts };
    hipError_t le = hipLaunchCooperativeKernel(reinterpret_cast<void*>(&k_pcg),
                                               dim3(NQUAD), dim3(NT), args, 0u, stream);
    if (le == hipSuccess) return;
    coop_ok = 0;    // launch rejected: permanently fall back
  }

  launch_fallback(E, DLp, Mm, lam, mu, wgp, xout, d_ws, stream);
}